// Round 10
// baseline (321.504 us; speedup 1.0000x reference)
//
#include <hip/hip_runtime.h>
#include <hip/hip_fp16.h>

#define FDIM 64
#define BLK 256

typedef float f32x4 __attribute__((ext_vector_type(4)));
typedef int   i32x4 __attribute__((ext_vector_type(4)));

// ---------------- build: hist -> bump-alloc -> fill ----------------
__global__ void dmpnn_hist(const int* __restrict__ recv, int* __restrict__ counts, int M) {
    int e = blockIdx.x * blockDim.x + threadIdx.x;
    if (e >= M) return;
    atomicAdd(&counts[recv[e]], 1);
}

// Block-local exclusive scan + one global bump per block. Perm layout is
// nondeterministic across blocks, but pooled sums are order-independent
// up to f16 rounding (well under threshold; R7 validated this scheme).
__global__ void dmpnn_alloc(const int* __restrict__ counts,
                            int* __restrict__ cursor,
                            int* __restrict__ gcounter, int N) {
    __shared__ int s[BLK];
    __shared__ int sbase;
    int t = blockIdx.x * BLK + threadIdx.x;
    int c = (t < N) ? counts[t] : 0;
    s[threadIdx.x] = c;
    __syncthreads();
    for (int d = 1; d < BLK; d <<= 1) {
        int v = (threadIdx.x >= (unsigned)d) ? s[threadIdx.x - d] : 0;
        __syncthreads();
        s[threadIdx.x] += v;
        __syncthreads();
    }
    if (threadIdx.x == BLK - 1) sbase = atomicAdd(gcounter, s[BLK - 1]);
    __syncthreads();
    if (t < N) cursor[t] = sbase + s[threadIdx.x] - c;
}

__global__ void dmpnn_fill(const int* __restrict__ recv,
                           int* __restrict__ cursor,
                           int* __restrict__ perm,
                           int* __restrict__ nodeOf, int M) {
    int e = blockIdx.x * blockDim.x + threadIdx.x;
    if (e >= M) return;
    int n = recv[e];
    int pos = atomicAdd(&cursor[n], 1);
    perm[pos] = e;
    nodeOf[pos] = n;
}

// ---------------- flat edge-centric aggregate ----------------
// Each 16-lane group owns 8 consecutive perm slots. 8 independent row
// loads in flight (gather_sub's proven shape); in-register run detection;
// pk-f16 atomic flush per run (~169K row-flushes x 128 B ~= 22 MB atomic
// bytes vs the 256 MB write-through wall of the naive scatter).
__global__ void dmpnn_aggregate(const float4* __restrict__ edges4f,
                                const int* __restrict__ perm,
                                const int* __restrict__ nodeOf,
                                __half2* __restrict__ pooled, int M) {
    const f32x4* edges4 = (const f32x4*)edges4f;
    long long tid = (long long)blockIdx.x * blockDim.x + threadIdx.x;
    long long grp = tid >> 4;
    int q = (int)(tid & 15);
    long long g0 = grp << 3;           // first of 8 slots
    if (g0 >= M) return;
    int cnt = (int)(M - g0); if (cnt > 8) cnt = 8;

    // Broadcast loads (same address across the 16 lanes of a group).
    const i32x4* p4 = (const i32x4*)(perm + g0);
    const i32x4* n4 = (const i32x4*)(nodeOf + g0);
    i32x4 pa = p4[0], pb = p4[1];
    i32x4 na = n4[0], nb = n4[1];
    int ee[8] = {pa.x, pa.y, pa.z, pa.w, pb.x, pb.y, pb.z, pb.w};
    int nn[8] = {na.x, na.y, na.z, na.w, nb.x, nb.y, nb.z, nb.w};

    f32x4 v[8];
    #pragma unroll
    for (int k = 0; k < 8; ++k) {
        int e = (k < cnt) ? ee[k] : ee[0];
        v[k] = __builtin_nontemporal_load(&edges4[(long long)e * 16 + q]);
    }

    f32x4 acc = v[0];
    int curn = nn[0];
    #pragma unroll
    for (int k = 1; k < 8; ++k) {
        if (k < cnt) {
            if (nn[k] == curn) {
                acc += v[k];
            } else {
                __half2* dst = &pooled[((long long)curn << 5) + (q << 1)];
                unsafeAtomicAdd(dst + 0, __floats2half2_rn(acc.x, acc.y));
                unsafeAtomicAdd(dst + 1, __floats2half2_rn(acc.z, acc.w));
                acc = v[k];
                curn = nn[k];
            }
        }
    }
    __half2* dst = &pooled[((long long)curn << 5) + (q << 1)];
    unsafeAtomicAdd(dst + 0, __floats2half2_rn(acc.x, acc.y));
    unsafeAtomicAdd(dst + 1, __floats2half2_rn(acc.z, acc.w));
}

// ---------------- Pass 2: gather + subtract, NT stores ----------------
__global__ void dmpnn_gather_sub(const __half2* __restrict__ pooled,
                                 const float4* __restrict__ edges4,
                                 const int* __restrict__ send,
                                 const int* __restrict__ pair,
                                 float4* __restrict__ out4,
                                 long long total /* = M * 16 */) {
    long long tid = (long long)blockIdx.x * blockDim.x + threadIdx.x;
    if (tid >= total) return;
    int e = (int)(tid >> 4);
    int q = (int)(tid & 15);
    int sn = send[e];
    int pe = pair[e];
    const __half2* ph = &pooled[((long long)sn << 5) + (q << 1)];
    __half2 h0 = ph[0];
    __half2 h1 = ph[1];
    float2 a0 = __half22float2(h0);
    float2 a1 = __half22float2(h1);
    float4 b = edges4[(long long)pe * 16 + q];
    f32x4 r;
    r.x = a0.x - b.x;
    r.y = a0.y - b.y;
    r.z = a1.x - b.z;
    r.w = a1.y - b.w;
    __builtin_nontemporal_store(r, (f32x4*)&out4[tid]);
}

// ---------------- fallback: R9 packed-atomic scatter ----------------
__global__ void dmpnn_scatter_h2(const float4* __restrict__ edges4,
                                 const int* __restrict__ recv,
                                 __half2* __restrict__ pooled,
                                 long long total /* = M * 16 */) {
    long long tid = (long long)blockIdx.x * blockDim.x + threadIdx.x;
    if (tid >= total) return;
    int e = (int)(tid >> 4);
    int g = (int)(tid & 15);
    float4 v = edges4[tid];
    int node = recv[e];
    __half2* dst = &pooled[((long long)node << 5) + (g << 1)];
    unsafeAtomicAdd(dst + 0, __floats2half2_rn(v.x, v.y));
    unsafeAtomicAdd(dst + 1, __floats2half2_rn(v.z, v.w));
}

extern "C" void kernel_launch(void* const* d_in, const int* in_sizes, int n_in,
                              void* d_out, int out_size, void* d_ws, size_t ws_size,
                              hipStream_t stream) {
    const float* edges      = (const float*)d_in[1];
    const int*   edge_index = (const int*)d_in[2];   // [2, M] flat
    const int*   edge_pairs = (const int*)d_in[3];   // [1, M] flat

    const int N = in_sizes[0] / FDIM;   // 50000
    const int M = in_sizes[1] / FDIM;   // 1000000

    const int* recv = edge_index;
    const int* send = edge_index + M;

    const size_t Np = (size_t)((N + 3) & ~3);
    const size_t Mp = (size_t)((M + 7) & ~7);

    // ws (ints): counts[Np] | gcounter[4] | cursor[Np] | perm[Mp] | nodeOf[Mp]
    //            then pooled: N*FDIM halves
    size_t need = (2 * Np + 4 + 2 * Mp) * sizeof(int)
                + (size_t)N * FDIM * sizeof(__half);

    long long total16 = (long long)M * 16;
    unsigned grid16 = (unsigned)((total16 + BLK - 1) / BLK);

    if (ws_size >= need) {
        int*     counts   = (int*)d_ws;
        int*     gcounter = counts + Np;
        int*     cursor   = gcounter + 4;
        int*     perm     = cursor + Np;
        int*     nodeOf   = perm + Mp;
        __half2* pooled   = (__half2*)(nodeOf + Mp);

        (void)hipMemsetAsync(counts, 0, (Np + 4) * sizeof(int), stream);
        (void)hipMemsetAsync(pooled, 0, (size_t)N * FDIM * sizeof(__half), stream);

        dmpnn_hist<<<dim3((M + BLK - 1) / BLK), dim3(BLK), 0, stream>>>(recv, counts, M);
        dmpnn_alloc<<<dim3((N + BLK - 1) / BLK), dim3(BLK), 0, stream>>>(counts, cursor, gcounter, N);
        dmpnn_fill<<<dim3((M + BLK - 1) / BLK), dim3(BLK), 0, stream>>>(recv, cursor, perm, nodeOf, M);

        {
            long long groups = (M + 7) / 8;            // 8 slots per 16-lane group
            long long threads = groups * 16;
            dmpnn_aggregate<<<dim3((unsigned)((threads + BLK - 1) / BLK)), dim3(BLK), 0, stream>>>(
                (const float4*)edges, perm, nodeOf, pooled, M);
        }

        dmpnn_gather_sub<<<dim3(grid16), dim3(BLK), 0, stream>>>(
            pooled, (const float4*)edges, send, edge_pairs,
            (float4*)d_out, total16);
    } else {
        __half2* pooled = (__half2*)d_ws;
        (void)hipMemsetAsync(pooled, 0, (size_t)N * FDIM * sizeof(__half), stream);
        dmpnn_scatter_h2<<<dim3(grid16), dim3(BLK), 0, stream>>>(
            (const float4*)edges, recv, pooled, total16);
        dmpnn_gather_sub<<<dim3(grid16), dim3(BLK), 0, stream>>>(
            pooled, (const float4*)edges, send, edge_pairs,
            (float4*)d_out, total16);
    }
}